// Round 5
// baseline (165.276 us; speedup 1.0000x reference)
//
#include <hip/hip_runtime.h>
#include <cstdint>
#include <cstddef>

// Problem constants (match reference)
#define BATCH 16
#define NBLK 16
#define TB 256
#define EMBED 2048
#define NKV 8
#define GQ 4          // group size = NH / NKV
#define HD 64
#define NQROWS 3072   // 2048 (q) + 512 (k_cur) + 512 (v_cur)
#define TTOT 4096     // NBLK * TB (score/p arrays cover all slots; mask in softmax)
#define QSCALE 0.18033688011112042f  // 64^-0.5 * log2(e)

// Workspace layout (floats):
#define OFF_SUMS   49152                 // [B][NKV][GQ]            (512)
#define OFF_PCUR   49664                 // [B][NKV][GQ]            (512)
#define OFF_PARTO  50176                 // [B][NKV][GQ][NBLK][HD]  (524288)
#define OFF_ATTEN  574464                // [B][EMBED]              (32768)
#define OFF_S      607232                // [B][NKV][TTOT][GQ]      (2097152)
#define OFF_P      2704384               // [B][NKV][GQ][TTOT]      (2097152)
// total 4,801,536 floats = 19.2 MB

__device__ __forceinline__ float dot4(float4 a, float4 b) {
  return a.x * b.x + a.y * b.y + a.z * b.z + a.w * b.w;
}

template <int CTRL>
__device__ __forceinline__ float dpp_add(float x) {
  return x + __int_as_float(
                 __builtin_amdgcn_mov_dpp(__float_as_int(x), CTRL, 0xF, 0xF, true));
}

// ---------------------------------------------------------------------------
// Kernel 1: fused q/k/v projection.  proj[b][i] = dot(W_all[i], x[b])
// ---------------------------------------------------------------------------
#define PROJ_RPB 4
__global__ __launch_bounds__(256) void proj_kernel(
    const float* __restrict__ x, const float* __restrict__ Wq,
    const float* __restrict__ Wk, const float* __restrict__ Wv,
    float* __restrict__ proj) {
  int tid = threadIdx.x;
  int bb = tid & 15, kc = tid >> 4;
  int row0 = blockIdx.x * PROJ_RPB;
  const float* xp = x + (size_t)bb * EMBED + kc * 128;
  const float* wr[PROJ_RPB];
#pragma unroll
  for (int r = 0; r < PROJ_RPB; ++r) {
    int row = row0 + r;
    wr[r] = (row < 2048 ? Wq + (size_t)row * EMBED
             : row < 2560 ? Wk + (size_t)(row - 2048) * EMBED
                          : Wv + (size_t)(row - 2560) * EMBED) + kc * 128;
  }
  float a[PROJ_RPB] = {0.f, 0.f, 0.f, 0.f};
#pragma unroll
  for (int k = 0; k < 128; k += 8) {
    float4 x0 = *reinterpret_cast<const float4*>(xp + k);
    float4 x1 = *reinterpret_cast<const float4*>(xp + k + 4);
#pragma unroll
    for (int r = 0; r < PROJ_RPB; ++r) {
      float4 w0 = *reinterpret_cast<const float4*>(wr[r] + k);
      float4 w1 = *reinterpret_cast<const float4*>(wr[r] + k + 4);
      a[r] += dot4(w0, x0) + dot4(w1, x1);
    }
  }
  int w = tid >> 6, lane = tid & 63;
  __shared__ float red[4][PROJ_RPB][16];
#pragma unroll
  for (int r = 0; r < PROJ_RPB; ++r) {
    float s = a[r];
    s += __shfl_xor(s, 16);
    s += __shfl_xor(s, 32);
    if (lane < 16) red[w][r][lane] = s;
  }
  __syncthreads();
  if (tid < 16 * PROJ_RPB) {
    int r = tid >> 4, b2 = tid & 15;
    float v = red[0][r][b2] + red[1][r][b2] + red[2][r][b2] + red[3][r][b2];
    proj[(size_t)b2 * NQROWS + row0 + r] = v;
  }
}

// ---------------------------------------------------------------------------
// Kernel 2: score pass — pure K stream.
// Grid (NBLK, BATCH, NKV) x 256. 4 lanes per token (16 dims each).
// Raw scores (no scale, no mask) -> sbuf[b][h][t][gi], 256B/instr stores.
// ---------------------------------------------------------------------------
__global__ __launch_bounds__(256) void score_kernel(
    const float* __restrict__ blocks_k, const float* __restrict__ proj,
    float* __restrict__ sbuf) {
  int nb = blockIdx.x, b = blockIdx.y, h = blockIdx.z;
  int tid = threadIdx.x;
  int w = tid >> 6, lane = tid & 63;
  int tq = lane >> 2;        // token within 16-token group
  int qd = lane & 3;         // quad position: dims [qd*16, qd*16+16)

  // q fragments: 16 dims per lane for each of the 4 query heads
  float4 qv[GQ][4];
  const float* qbase = proj + (size_t)b * NQROWS + h * GQ * HD + qd * 16;
#pragma unroll
  for (int gi = 0; gi < GQ; ++gi)
#pragma unroll
    for (int j = 0; j < 4; ++j)
      qv[gi][j] = *reinterpret_cast<const float4*>(qbase + gi * HD + j * 4);

  const float* kg = blocks_k + (((size_t)nb * BATCH + b) * NKV + h) * (TB * HD);
  float* sout = sbuf + ((size_t)(b * NKV + h)) * (TTOT * GQ) +
                (size_t)(nb * TB + w * 64) * GQ;

#pragma unroll
  for (int i = 0; i < 4; ++i) {
    int tl = w * 64 + i * 16 + tq;
    const float* kp = kg + (size_t)tl * HD + qd * 16;
    float4 k0 = *reinterpret_cast<const float4*>(kp);
    float4 k1 = *reinterpret_cast<const float4*>(kp + 4);
    float4 k2 = *reinterpret_cast<const float4*>(kp + 8);
    float4 k3 = *reinterpret_cast<const float4*>(kp + 12);
    float s[GQ];
#pragma unroll
    for (int gi = 0; gi < GQ; ++gi) {
      s[gi] = dot4(qv[gi][0], k0) + dot4(qv[gi][1], k1) +
              dot4(qv[gi][2], k2) + dot4(qv[gi][3], k3);
      // quad reduction: sum the 4 lanes of this token
      s[gi] = dpp_add<0xB1>(s[gi]);  // quad_perm xor 1
      s[gi] = dpp_add<0x4E>(s[gi]);  // quad_perm xor 2
    }
    // lane stores s[qd] at column qd -> 64 contiguous floats per instr
    float v01 = (qd & 1) ? s[1] : s[0];
    float v23 = (qd & 1) ? s[3] : s[2];
    float v = (qd & 2) ? v23 : v01;
    sout[(size_t)(i * 16) * GQ + lane] = v;
  }
}

// ---------------------------------------------------------------------------
// Kernel 3: softmax over the full row (exact, two passes over L2-hot scores).
// Grid: 128 blocks (= B*NKV) x 256; wave w handles gi = w.
// Writes unnormalized p (0 for masked), row sum (incl current), p_cur.
// ---------------------------------------------------------------------------
__global__ __launch_bounds__(256) void softmax_kernel(
    const float* __restrict__ sbuf, const float* __restrict__ proj,
    const int* __restrict__ last_offset, float* __restrict__ pbuf,
    float* __restrict__ sums, float* __restrict__ pcur) {
  int bh = blockIdx.x;           // b*NKV + h
  int b = bh >> 3, h = bh & 7;
  int gi = threadIdx.x >> 6, lane = threadIdx.x & 63;
  int valid = (NBLK - 1) * TB + last_offset[0];

  const float* srow = sbuf + (size_t)bh * (TTOT * GQ);
  float* prow = pbuf + ((size_t)bh * GQ + gi) * TTOT;

  // current-token raw score: q[b,h,gi,:] . k_cur[b,h,:]
  float qd = proj[(size_t)b * NQROWS + (h * GQ + gi) * HD + lane];
  float kd = proj[(size_t)b * NQROWS + 2048 + h * HD + lane];
  float sp = qd * kd;
#pragma unroll
  for (int mask = 1; mask < 64; mask <<= 1) sp += __shfl_xor(sp, mask);
  float s_cur = sp;

  // pass A: max over valid positions
  float mx = s_cur;
#pragma unroll 8
  for (int i = 0; i < TTOT / 64; ++i) {
    int t = i * 64 + lane;
    float v = srow[(size_t)t * GQ + gi];
    if (t < valid) mx = fmaxf(mx, v);
  }
#pragma unroll
  for (int mask = 1; mask < 64; mask <<= 1) mx = fmaxf(mx, __shfl_xor(mx, mask));

  // pass B: exp, sum, write p
  float sum = 0.f;
#pragma unroll 8
  for (int i = 0; i < TTOT / 64; ++i) {
    int t = i * 64 + lane;
    float v = srow[(size_t)t * GQ + gi];
    float p = (t < valid) ? exp2f((v - mx) * QSCALE) : 0.f;
    sum += p;
    prow[t] = p;
  }
#pragma unroll
  for (int mask = 1; mask < 64; mask <<= 1) sum += __shfl_xor(sum, mask);
  float p_c = exp2f((s_cur - mx) * QSCALE);
  if (lane == 0) {
    sums[bh * GQ + gi] = sum + p_c;
    pcur[bh * GQ + gi] = p_c;
  }
}

// ---------------------------------------------------------------------------
// Kernel 4: PV pass — pure V stream.
// Grid (NBLK, BATCH, NKV) x 256. 16 lanes per token (4 dims each).
// acc[gi] += p[gi][t] * v4. Partial sums per cache block -> part_o.
// ---------------------------------------------------------------------------
__global__ __launch_bounds__(256) void pv_kernel(
    const float* __restrict__ blocks_v, const float* __restrict__ pbuf,
    float* __restrict__ part_o) {
  int nb = blockIdx.x, b = blockIdx.y, h = blockIdx.z;
  int tid = threadIdx.x;
  int w = tid >> 6, lane = tid & 63;
  int sub = lane >> 4, dl = (lane & 15) * 4;

  const float* vg = blocks_v + (((size_t)nb * BATCH + b) * NKV + h) * (TB * HD);
  const float* pg = pbuf + ((size_t)(b * NKV + h)) * (GQ * TTOT) + nb * TB;

  float4 acc[GQ];
#pragma unroll
  for (int gi = 0; gi < GQ; ++gi) acc[gi] = make_float4(0.f, 0.f, 0.f, 0.f);

#pragma unroll
  for (int i = 0; i < 16; ++i) {
    int tl = w * 64 + i * 4 + sub;
    float4 v4 = *reinterpret_cast<const float4*>(vg + (size_t)tl * HD + dl);
    float p0 = pg[0 * TTOT + tl];
    float p1 = pg[1 * TTOT + tl];
    float p2 = pg[2 * TTOT + tl];
    float p3 = pg[3 * TTOT + tl];
    acc[0].x += p0 * v4.x; acc[0].y += p0 * v4.y; acc[0].z += p0 * v4.z; acc[0].w += p0 * v4.w;
    acc[1].x += p1 * v4.x; acc[1].y += p1 * v4.y; acc[1].z += p1 * v4.z; acc[1].w += p1 * v4.w;
    acc[2].x += p2 * v4.x; acc[2].y += p2 * v4.y; acc[2].z += p2 * v4.z; acc[2].w += p2 * v4.w;
    acc[3].x += p3 * v4.x; acc[3].y += p3 * v4.y; acc[3].z += p3 * v4.z; acc[3].w += p3 * v4.w;
  }

  // merge the 4 token sub-slots (plain adds)
#pragma unroll
  for (int mask = 16; mask <= 32; mask <<= 1) {
#pragma unroll
    for (int gi = 0; gi < GQ; ++gi) {
      acc[gi].x += __shfl_xor(acc[gi].x, mask);
      acc[gi].y += __shfl_xor(acc[gi].y, mask);
      acc[gi].z += __shfl_xor(acc[gi].z, mask);
      acc[gi].w += __shfl_xor(acc[gi].w, mask);
    }
  }

  __shared__ float lds_o[4][GQ][HD];
  if (lane < 16) {
#pragma unroll
    for (int gi = 0; gi < GQ; ++gi)
      *reinterpret_cast<float4*>(&lds_o[w][gi][dl]) = acc[gi];
  }
  __syncthreads();
  if (w == 0) {
    int d = lane;
#pragma unroll
    for (int gi = 0; gi < GQ; ++gi) {
      float o = lds_o[0][gi][d] + lds_o[1][gi][d] + lds_o[2][gi][d] + lds_o[3][gi][d];
      part_o[(((size_t)(b * NKV + h) * GQ + gi) * NBLK + nb) * HD + d] = o;
    }
  }
}

// ---------------------------------------------------------------------------
// Kernel 5: merge block partials + current token, normalize.
// Grid: 128 blocks x 256; one wave per (b,h,gi).
// ---------------------------------------------------------------------------
__global__ __launch_bounds__(256) void reduce_kernel(
    const float* __restrict__ proj, const float* __restrict__ part_o,
    const float* __restrict__ sums, const float* __restrict__ pcur,
    float* __restrict__ atten) {
  int tid = threadIdx.x;
  int wi = blockIdx.x * 4 + (tid >> 6);
  int lane = tid & 63;  // head-dim d
  int b = wi >> 5;
  int h = (wi >> 2) & 7;
  int gi = wi & 3;
  size_t pidx = ((size_t)(b * NKV + h) * GQ + gi) * NBLK;

  float vd = proj[(size_t)b * NQROWS + 2560 + h * HD + lane];
  float o = pcur[wi] * vd;
#pragma unroll
  for (int nb = 0; nb < NBLK; ++nb) o += part_o[(pidx + nb) * HD + lane];
  atten[(size_t)b * EMBED + (h * GQ + gi) * HD + lane] = o / sums[wi];
}

// ---------------------------------------------------------------------------
// Kernel 6: out[b][i] = dot(Wo[i], atten[b])
// ---------------------------------------------------------------------------
#define OUT_RPB 4
__global__ __launch_bounds__(256) void out_kernel(
    const float* __restrict__ atten, const float* __restrict__ Wo,
    float* __restrict__ out) {
  int tid = threadIdx.x;
  int bb = tid & 15, kc = tid >> 4;
  int row0 = blockIdx.x * OUT_RPB;
  const float* xp = atten + (size_t)bb * EMBED + kc * 128;
  float a[OUT_RPB] = {0.f, 0.f, 0.f, 0.f};
#pragma unroll
  for (int k = 0; k < 128; k += 8) {
    float4 x0 = *reinterpret_cast<const float4*>(xp + k);
    float4 x1 = *reinterpret_cast<const float4*>(xp + k + 4);
#pragma unroll
    for (int r = 0; r < OUT_RPB; ++r) {
      const float* wp = Wo + (size_t)(row0 + r) * EMBED + kc * 128;
      float4 w0 = *reinterpret_cast<const float4*>(wp + k);
      float4 w1 = *reinterpret_cast<const float4*>(wp + k + 4);
      a[r] += dot4(w0, x0) + dot4(w1, x1);
    }
  }
  int w = tid >> 6, lane = tid & 63;
  __shared__ float red[4][OUT_RPB][16];
#pragma unroll
  for (int r = 0; r < OUT_RPB; ++r) {
    float s = a[r];
    s += __shfl_xor(s, 16);
    s += __shfl_xor(s, 32);
    if (lane < 16) red[w][r][lane] = s;
  }
  __syncthreads();
  if (tid < 16 * OUT_RPB) {
    int r = tid >> 4, b2 = tid & 15;
    float v = red[0][r][b2] + red[1][r][b2] + red[2][r][b2] + red[3][r][b2];
    out[(size_t)b2 * EMBED + row0 + r] = v;
  }
}

// ---------------------------------------------------------------------------
extern "C" void kernel_launch(void* const* d_in, const int* in_sizes, int n_in,
                              void* d_out, int out_size, void* d_ws, size_t ws_size,
                              hipStream_t stream) {
  const float* x = (const float*)d_in[0];
  const float* bk = (const float*)d_in[1];
  const float* bv = (const float*)d_in[2];
  const float* Wq = (const float*)d_in[3];
  const float* Wk = (const float*)d_in[4];
  const float* Wv = (const float*)d_in[5];
  const float* Wo = (const float*)d_in[6];
  const int* lo = (const int*)d_in[7];

  float* ws = (float*)d_ws;
  float* proj = ws;
  float* sums = ws + OFF_SUMS;
  float* pcur = ws + OFF_PCUR;
  float* part_o = ws + OFF_PARTO;
  float* atten = ws + OFF_ATTEN;
  float* sbuf = ws + OFF_S;
  float* pbuf = ws + OFF_P;
  float* out = (float*)d_out;

  proj_kernel<<<NQROWS / PROJ_RPB, 256, 0, stream>>>(x, Wq, Wk, Wv, proj);
  score_kernel<<<dim3(NBLK, BATCH, NKV), 256, 0, stream>>>(bk, proj, sbuf);
  softmax_kernel<<<BATCH * NKV, 256, 0, stream>>>(sbuf, proj, lo, pbuf, sums, pcur);
  pv_kernel<<<dim3(NBLK, BATCH, NKV), 256, 0, stream>>>(bv, pbuf, part_o);
  reduce_kernel<<<(BATCH * NKV * GQ) / 4, 256, 0, stream>>>(proj, part_o, sums,
                                                            pcur, atten);
  out_kernel<<<EMBED / OUT_RPB, 256, 0, stream>>>(atten, Wo, out);
}

// Round 6
// 141.625 us; speedup vs baseline: 1.1670x; 1.1670x over previous
//
#include <hip/hip_runtime.h>
#include <cstdint>
#include <cstddef>

// Problem constants (match reference)
#define BATCH 16
#define NBLK 16
#define TB 256
#define EMBED 2048
#define NKV 8
#define GQ 4          // group size = NH / NKV
#define HD 64
#define NQROWS 3072   // 2048 (q) + 512 (k_cur) + 512 (v_cur)
#define TTOT 4096     // NBLK * TB
#define QSCALE 0.18033688011112042f  // 64^-0.5 * log2(e)
#define NEGBIG (-1e30f)

// Workspace layout (floats):
#define OFF_PARTM  49152                 // [B*NKV*GQ][64]        (32768)
#define OFF_PARTS  81920                 // [B*NKV*GQ][64]        (32768)
#define OFF_CMB    114688                // [B*NKV*GQ] float4     (2048)
#define OFF_PARTO  116736                // [B*NKV*GQ][NBLK][HD]  (524288)
#define OFF_ATTEN  641024                // [B][EMBED]            (32768)
#define OFF_S      673792                // [B*NKV][TTOT][GQ]     (2097152)

__device__ __forceinline__ float dot4(float4 a, float4 b) {
  return a.x * b.x + a.y * b.y + a.z * b.z + a.w * b.w;
}

template <int CTRL>
__device__ __forceinline__ float dpp_add(float x) {
  return x + __int_as_float(
                 __builtin_amdgcn_mov_dpp(__float_as_int(x), CTRL, 0xF, 0xF, true));
}

// ---------------------------------------------------------------------------
// Kernel 1: fused q/k/v projection.  proj[b][i] = dot(W_all[i], x[b])
// ---------------------------------------------------------------------------
#define PROJ_RPB 4
__global__ __launch_bounds__(256) void proj_kernel(
    const float* __restrict__ x, const float* __restrict__ Wq,
    const float* __restrict__ Wk, const float* __restrict__ Wv,
    float* __restrict__ proj) {
  int tid = threadIdx.x;
  int bb = tid & 15, kc = tid >> 4;
  int row0 = blockIdx.x * PROJ_RPB;
  const float* xp = x + (size_t)bb * EMBED + kc * 128;
  const float* wr[PROJ_RPB];
#pragma unroll
  for (int r = 0; r < PROJ_RPB; ++r) {
    int row = row0 + r;
    wr[r] = (row < 2048 ? Wq + (size_t)row * EMBED
             : row < 2560 ? Wk + (size_t)(row - 2048) * EMBED
                          : Wv + (size_t)(row - 2560) * EMBED) + kc * 128;
  }
  float a[PROJ_RPB] = {0.f, 0.f, 0.f, 0.f};
#pragma unroll
  for (int k = 0; k < 128; k += 8) {
    float4 x0 = *reinterpret_cast<const float4*>(xp + k);
    float4 x1 = *reinterpret_cast<const float4*>(xp + k + 4);
#pragma unroll
    for (int r = 0; r < PROJ_RPB; ++r) {
      float4 w0 = *reinterpret_cast<const float4*>(wr[r] + k);
      float4 w1 = *reinterpret_cast<const float4*>(wr[r] + k + 4);
      a[r] += dot4(w0, x0) + dot4(w1, x1);
    }
  }
  int w = tid >> 6, lane = tid & 63;
  __shared__ float red[4][PROJ_RPB][16];
#pragma unroll
  for (int r = 0; r < PROJ_RPB; ++r) {
    float s = a[r];
    s += __shfl_xor(s, 16);
    s += __shfl_xor(s, 32);
    if (lane < 16) red[w][r][lane] = s;
  }
  __syncthreads();
  if (tid < 16 * PROJ_RPB) {
    int r = tid >> 4, b2 = tid & 15;
    float v = red[0][r][b2] + red[1][r][b2] + red[2][r][b2] + red[3][r][b2];
    proj[(size_t)b2 * NQROWS + row0 + r] = v;
  }
}

// ---------------------------------------------------------------------------
// Kernel 2: score pass — pure K stream + fused per-wave online (max, sumexp).
// Grid (NBLK, BATCH, NKV) x 256. 4 lanes per token (16 dims each).
// Raw scores -> sbuf[bh][t][gi] (invalid slots get NEGBIG).
// Per-wave partials -> part_m/part_s at [wi][nb*4+w].
// ---------------------------------------------------------------------------
__global__ __launch_bounds__(256) void score_kernel(
    const float* __restrict__ blocks_k, const float* __restrict__ proj,
    const int* __restrict__ last_offset, float* __restrict__ sbuf,
    float* __restrict__ part_m, float* __restrict__ part_s) {
  int nb = blockIdx.x, b = blockIdx.y, h = blockIdx.z;
  int tid = threadIdx.x;
  int w = tid >> 6, lane = tid & 63;
  int tq = lane >> 2;        // token within 16-token group
  int qd = lane & 3;         // quad position: dims [qd*16, qd*16+16)
  int valid = (nb == NBLK - 1) ? last_offset[0] : TB;

  // q fragments: 16 dims per lane for each of the 4 query heads
  float4 qv[GQ][4];
  const float* qbase = proj + (size_t)b * NQROWS + h * GQ * HD + qd * 16;
#pragma unroll
  for (int gi = 0; gi < GQ; ++gi)
#pragma unroll
    for (int j = 0; j < 4; ++j)
      qv[gi][j] = *reinterpret_cast<const float4*>(qbase + gi * HD + j * 4);

  const float* kg = blocks_k + (((size_t)nb * BATCH + b) * NKV + h) * (TB * HD);
  float* sout = sbuf + ((size_t)(b * NKV + h)) * (TTOT * GQ) +
                (size_t)(nb * TB + w * 64) * GQ;

  float m[GQ], sm[GQ];
#pragma unroll
  for (int gi = 0; gi < GQ; ++gi) { m[gi] = NEGBIG; sm[gi] = 0.f; }

#pragma unroll
  for (int i = 0; i < 4; ++i) {
    int tl = w * 64 + i * 16 + tq;
    const float* kp = kg + (size_t)tl * HD + qd * 16;
    float4 k0 = *reinterpret_cast<const float4*>(kp);
    float4 k1 = *reinterpret_cast<const float4*>(kp + 4);
    float4 k2 = *reinterpret_cast<const float4*>(kp + 8);
    float4 k3 = *reinterpret_cast<const float4*>(kp + 12);
    float s[GQ];
#pragma unroll
    for (int gi = 0; gi < GQ; ++gi) {
      s[gi] = dot4(qv[gi][0], k0) + dot4(qv[gi][1], k1) +
              dot4(qv[gi][2], k2) + dot4(qv[gi][3], k3);
      s[gi] = dpp_add<0xB1>(s[gi]);  // quad_perm xor 1
      s[gi] = dpp_add<0x4E>(s[gi]);  // quad_perm xor 2
      s[gi] = (tl < valid) ? s[gi] : NEGBIG;
    }
    // online per-wave (max, sumexp) over the 16 tokens of this iteration
#pragma unroll
    for (int gi = 0; gi < GQ; ++gi) {
      float im = s[gi];
#pragma unroll
      for (int mask = 4; mask < 64; mask <<= 1) im = fmaxf(im, __shfl_xor(im, mask));
      float mn = fmaxf(m[gi], im);
      float c = exp2f((m[gi] - mn) * QSCALE);
      float e = exp2f((s[gi] - mn) * QSCALE);
      float es = e;
#pragma unroll
      for (int mask = 4; mask < 64; mask <<= 1) es += __shfl_xor(es, mask);
      sm[gi] = sm[gi] * c + es;
      m[gi] = mn;
    }
    // store raw scores: token tq, column qd -> contiguous 256B per wave
    float v01 = (qd & 1) ? s[1] : s[0];
    float v23 = (qd & 1) ? s[3] : s[2];
    float v = (qd & 2) ? v23 : v01;
    sout[(size_t)(i * 16) * GQ + lane] = v;
  }

  if (lane == 0) {
#pragma unroll
    for (int gi = 0; gi < GQ; ++gi) {
      size_t wi = ((size_t)(b * NKV + h) * GQ + gi);
      part_m[wi * 64 + nb * 4 + w] = m[gi];
      part_s[wi * 64 + nb * 4 + w] = sm[gi];
    }
  }
}

// ---------------------------------------------------------------------------
// Kernel 3: combine 64 wave-partials + current-token score per (b,h,gi).
// Grid: 128 blocks x 256; one wave per (b,h,gi).
// Writes cmb[wi] = {M, p_cur, 1/T, 0}.
// ---------------------------------------------------------------------------
__global__ __launch_bounds__(256) void combine_kernel(
    const float* __restrict__ proj, const float* __restrict__ part_m,
    const float* __restrict__ part_s, float4* __restrict__ cmb) {
  int tid = threadIdx.x;
  int wi = blockIdx.x * 4 + (tid >> 6);
  int lane = tid & 63;
  int b = wi >> 5;
  int h = (wi >> 2) & 7;
  int gi = wi & 3;

  float pm = part_m[(size_t)wi * 64 + lane];
  float ps = part_s[(size_t)wi * 64 + lane];

  // current-token raw score: q[b,h,gi,:] . k_cur[b,h,:]
  float qd = proj[(size_t)b * NQROWS + (h * GQ + gi) * HD + lane];
  float kd = proj[(size_t)b * NQROWS + 2048 + h * HD + lane];
  float sp = qd * kd;
#pragma unroll
  for (int mask = 1; mask < 64; mask <<= 1) sp += __shfl_xor(sp, mask);

  float M = pm;
#pragma unroll
  for (int mask = 1; mask < 64; mask <<= 1) M = fmaxf(M, __shfl_xor(M, mask));
  M = fmaxf(M, sp);

  float contrib = ps * exp2f((pm - M) * QSCALE);
#pragma unroll
  for (int mask = 1; mask < 64; mask <<= 1) contrib += __shfl_xor(contrib, mask);
  float p_cur = exp2f((sp - M) * QSCALE);
  float T = contrib + p_cur;
  if (lane == 0) cmb[wi] = make_float4(M, p_cur, 1.f / T, 0.f);
}

// ---------------------------------------------------------------------------
// Kernel 4: PV pass — pure V stream; p computed on the fly from raw scores.
// Grid (NBLK, BATCH, NKV) x 256. 16 lanes per token (4 dims each).
// ---------------------------------------------------------------------------
__global__ __launch_bounds__(256) void pv_kernel(
    const float* __restrict__ blocks_v, const float* __restrict__ sbuf,
    const float4* __restrict__ cmb, float* __restrict__ part_o) {
  int nb = blockIdx.x, b = blockIdx.y, h = blockIdx.z;
  int tid = threadIdx.x;
  int w = tid >> 6, lane = tid & 63;
  int sub = lane >> 4, dl = (lane & 15) * 4;

  const float* vg = blocks_v + (((size_t)nb * BATCH + b) * NKV + h) * (TB * HD);
  const float* sg = sbuf + ((size_t)(b * NKV + h)) * (TTOT * GQ) +
                    (size_t)(nb * TB) * GQ;

  // global maxes per query head
  float Mv[GQ];
#pragma unroll
  for (int gi = 0; gi < GQ; ++gi)
    Mv[gi] = cmb[(size_t)(b * NKV + h) * GQ + gi].x;

  float4 acc[GQ];
#pragma unroll
  for (int gi = 0; gi < GQ; ++gi) acc[gi] = make_float4(0.f, 0.f, 0.f, 0.f);

#pragma unroll
  for (int i = 0; i < 4; ++i) {
    // 16 tokens per iter: 4 groups of 4 (sub picks token within group)
    float4 v4[4], s4[4];
#pragma unroll
    for (int j = 0; j < 4; ++j) {
      int tl = w * 64 + i * 16 + j * 4 + sub;
      v4[j] = *reinterpret_cast<const float4*>(vg + (size_t)tl * HD + dl);
      s4[j] = *reinterpret_cast<const float4*>(sg + (size_t)tl * GQ);
    }
#pragma unroll
    for (int j = 0; j < 4; ++j) {
      float p0 = exp2f((s4[j].x - Mv[0]) * QSCALE);
      float p1 = exp2f((s4[j].y - Mv[1]) * QSCALE);
      float p2 = exp2f((s4[j].z - Mv[2]) * QSCALE);
      float p3 = exp2f((s4[j].w - Mv[3]) * QSCALE);
      acc[0].x += p0 * v4[j].x; acc[0].y += p0 * v4[j].y;
      acc[0].z += p0 * v4[j].z; acc[0].w += p0 * v4[j].w;
      acc[1].x += p1 * v4[j].x; acc[1].y += p1 * v4[j].y;
      acc[1].z += p1 * v4[j].z; acc[1].w += p1 * v4[j].w;
      acc[2].x += p2 * v4[j].x; acc[2].y += p2 * v4[j].y;
      acc[2].z += p2 * v4[j].z; acc[2].w += p2 * v4[j].w;
      acc[3].x += p3 * v4[j].x; acc[3].y += p3 * v4[j].y;
      acc[3].z += p3 * v4[j].z; acc[3].w += p3 * v4[j].w;
    }
  }

  // merge the 4 token sub-slots (plain adds)
#pragma unroll
  for (int mask = 16; mask <= 32; mask <<= 1) {
#pragma unroll
    for (int gi = 0; gi < GQ; ++gi) {
      acc[gi].x += __shfl_xor(acc[gi].x, mask);
      acc[gi].y += __shfl_xor(acc[gi].y, mask);
      acc[gi].z += __shfl_xor(acc[gi].z, mask);
      acc[gi].w += __shfl_xor(acc[gi].w, mask);
    }
  }

  __shared__ float lds_o[4][GQ][HD];
  if (lane < 16) {
#pragma unroll
    for (int gi = 0; gi < GQ; ++gi)
      *reinterpret_cast<float4*>(&lds_o[w][gi][dl]) = acc[gi];
  }
  __syncthreads();
  if (w == 0) {
    int d = lane;
#pragma unroll
    for (int gi = 0; gi < GQ; ++gi) {
      float o = lds_o[0][gi][d] + lds_o[1][gi][d] + lds_o[2][gi][d] + lds_o[3][gi][d];
      part_o[(((size_t)(b * NKV + h) * GQ + gi) * NBLK + nb) * HD + d] = o;
    }
  }
}

// ---------------------------------------------------------------------------
// Kernel 5: merge block partials + current token, normalize.
// Grid: 128 blocks x 256; one wave per (b,h,gi).
// ---------------------------------------------------------------------------
__global__ __launch_bounds__(256) void reduce_kernel(
    const float* __restrict__ proj, const float* __restrict__ part_o,
    const float4* __restrict__ cmb, float* __restrict__ atten) {
  int tid = threadIdx.x;
  int wi = blockIdx.x * 4 + (tid >> 6);
  int lane = tid & 63;  // head-dim d
  int b = wi >> 5;
  int h = (wi >> 2) & 7;
  int gi = wi & 3;
  size_t pidx = (size_t)wi * NBLK;

  float4 c4 = cmb[wi];
  float vd = proj[(size_t)b * NQROWS + 2560 + h * HD + lane];
  float o = c4.y * vd;
#pragma unroll
  for (int nb = 0; nb < NBLK; ++nb) o += part_o[(pidx + nb) * HD + lane];
  atten[(size_t)b * EMBED + (h * GQ + gi) * HD + lane] = o * c4.z;
}

// ---------------------------------------------------------------------------
// Kernel 6: out[b][i] = dot(Wo[i], atten[b])
// ---------------------------------------------------------------------------
#define OUT_RPB 4
__global__ __launch_bounds__(256) void out_kernel(
    const float* __restrict__ atten, const float* __restrict__ Wo,
    float* __restrict__ out) {
  int tid = threadIdx.x;
  int bb = tid & 15, kc = tid >> 4;
  int row0 = blockIdx.x * OUT_RPB;
  const float* xp = atten + (size_t)bb * EMBED + kc * 128;
  float a[OUT_RPB] = {0.f, 0.f, 0.f, 0.f};
#pragma unroll
  for (int k = 0; k < 128; k += 8) {
    float4 x0 = *reinterpret_cast<const float4*>(xp + k);
    float4 x1 = *reinterpret_cast<const float4*>(xp + k + 4);
#pragma unroll
    for (int r = 0; r < OUT_RPB; ++r) {
      const float* wp = Wo + (size_t)(row0 + r) * EMBED + kc * 128;
      float4 w0 = *reinterpret_cast<const float4*>(wp + k);
      float4 w1 = *reinterpret_cast<const float4*>(wp + k + 4);
      a[r] += dot4(w0, x0) + dot4(w1, x1);
    }
  }
  int w = tid >> 6, lane = tid & 63;
  __shared__ float red[4][OUT_RPB][16];
#pragma unroll
  for (int r = 0; r < OUT_RPB; ++r) {
    float s = a[r];
    s += __shfl_xor(s, 16);
    s += __shfl_xor(s, 32);
    if (lane < 16) red[w][r][lane] = s;
  }
  __syncthreads();
  if (tid < 16 * OUT_RPB) {
    int r = tid >> 4, b2 = tid & 15;
    float v = red[0][r][b2] + red[1][r][b2] + red[2][r][b2] + red[3][r][b2];
    out[(size_t)b2 * EMBED + row0 + r] = v;
  }
}

// ---------------------------------------------------------------------------
extern "C" void kernel_launch(void* const* d_in, const int* in_sizes, int n_in,
                              void* d_out, int out_size, void* d_ws, size_t ws_size,
                              hipStream_t stream) {
  const float* x = (const float*)d_in[0];
  const float* bk = (const float*)d_in[1];
  const float* bv = (const float*)d_in[2];
  const float* Wq = (const float*)d_in[3];
  const float* Wk = (const float*)d_in[4];
  const float* Wv = (const float*)d_in[5];
  const float* Wo = (const float*)d_in[6];
  const int* lo = (const int*)d_in[7];

  float* ws = (float*)d_ws;
  float* proj = ws;
  float* part_m = ws + OFF_PARTM;
  float* part_s = ws + OFF_PARTS;
  float4* cmb = (float4*)(ws + OFF_CMB);
  float* part_o = ws + OFF_PARTO;
  float* atten = ws + OFF_ATTEN;
  float* sbuf = ws + OFF_S;
  float* out = (float*)d_out;

  proj_kernel<<<NQROWS / PROJ_RPB, 256, 0, stream>>>(x, Wq, Wk, Wv, proj);
  score_kernel<<<dim3(NBLK, BATCH, NKV), 256, 0, stream>>>(bk, proj, lo, sbuf,
                                                           part_m, part_s);
  combine_kernel<<<(BATCH * NKV * GQ) / 4, 256, 0, stream>>>(proj, part_m,
                                                             part_s, cmb);
  pv_kernel<<<dim3(NBLK, BATCH, NKV), 256, 0, stream>>>(bv, sbuf, cmb, part_o);
  reduce_kernel<<<(BATCH * NKV * GQ) / 4, 256, 0, stream>>>(proj, part_o, cmb,
                                                            atten);
  out_kernel<<<EMBED / OUT_RPB, 256, 0, stream>>>(atten, Wo, out);
}